// Round 1
// baseline (101.389 us; speedup 1.0000x reference)
//
#include <hip/hip_runtime.h>
#include <hip/hip_bf16.h>
#include <stdint.h>

#define N_PTS 4096
#define DIM 512
#define MARGIN_F 0.3f
#define POS_INF_BITS 0x7f800000

typedef short bf16x8 __attribute__((ext_vector_type(8)));
typedef float f32x4 __attribute__((ext_vector_type(4)));

__device__ __forceinline__ unsigned short f2bf(float f) {
    unsigned int b = __float_as_uint(f);
    b += 0x7FFF + ((b >> 16) & 1);   // round-to-nearest-even
    return (unsigned short)(b >> 16);
}

// async global->LDS, 16B per lane; LDS dest is wave-uniform base + lane*16
__device__ __forceinline__ void async16(const unsigned short* g, unsigned short* l) {
    __builtin_amdgcn_global_load_lds(
        (const __attribute__((address_space(1))) unsigned int*)g,
        (__attribute__((address_space(3))) unsigned int*)l,
        16, 0, 0);
}

// Raw barrier / waitcnt: counted vmcnt in steady state, never 0 mid-loop.
#define RAW_BARRIER()  asm volatile("s_barrier" ::: "memory")
#define WAIT_VM4()     asm volatile("s_waitcnt vmcnt(4)" ::: "memory")
#define WAIT_VM0()     asm volatile("s_waitcnt vmcnt(0)" ::: "memory")

// One wave per row: bf16 copy + exact fp32 norms; zero the output accumulator.
__global__ __launch_bounds__(256) void prep_kernel(
    const float* __restrict__ src, const float* __restrict__ tgt,
    unsigned short* __restrict__ src_bf, unsigned short* __restrict__ tgt_bf,
    float* __restrict__ e1, float* __restrict__ e2,
    float* __restrict__ out)
{
    const int row  = blockIdx.x * 4 + (threadIdx.x >> 6);
    const int lane = threadIdx.x & 63;

    if (blockIdx.x == 0 && threadIdx.x == 0) out[0] = 0.0f;

    const float4* s4 = (const float4*)(src + (size_t)row * DIM);
    const float4* t4 = (const float4*)(tgt + (size_t)row * DIM);
    float4 a0 = s4[lane], a1 = s4[lane + 64];
    float4 b0 = t4[lane], b1 = t4[lane + 64];

    ushort4 u;
    ushort4* so = (ushort4*)(src_bf + (size_t)row * DIM);
    ushort4* to = (ushort4*)(tgt_bf + (size_t)row * DIM);
    u.x = f2bf(a0.x); u.y = f2bf(a0.y); u.z = f2bf(a0.z); u.w = f2bf(a0.w); so[lane] = u;
    u.x = f2bf(a1.x); u.y = f2bf(a1.y); u.z = f2bf(a1.z); u.w = f2bf(a1.w); so[lane + 64] = u;
    u.x = f2bf(b0.x); u.y = f2bf(b0.y); u.z = f2bf(b0.z); u.w = f2bf(b0.w); to[lane] = u;
    u.x = f2bf(b1.x); u.y = f2bf(b1.y); u.z = f2bf(b1.z); u.w = f2bf(b1.w); to[lane + 64] = u;

    float s1 = a0.x*a0.x + a0.y*a0.y + a0.z*a0.z + a0.w*a0.w
             + a1.x*a1.x + a1.y*a1.y + a1.z*a1.z + a1.w*a1.w;
    float s2 = b0.x*b0.x + b0.y*b0.y + b0.z*b0.z + b0.w*b0.w
             + b1.x*b1.x + b1.y*b1.y + b1.z*b1.z + b1.w*b1.w;
    for (int off = 32; off; off >>= 1) {
        s1 += __shfl_down(s1, off);
        s2 += __shfl_down(s2, off);
    }
    if (lane == 0) {
        e1[row] = s1;
        e2[row] = s2;
    }
}

#define BM 128
#define BN 128
#define BK 32
#define NSTEP (DIM / BK)   // 16
#define NPART 64           // 32 col-blocks x 2 col-waves

// r11 retile: occupancy over LDS-traffic-per-output. Counters (r10 kernel)
// showed latency/sync-bound: MfmaUtil 10.7%, VALUBusy 13.5%, occupancy 20%
// (2 blocks/CU x 4 waves = 2 waves/SIMD, grid 512 = exact capacity, zero
// slack). All throughput floors (MFMA ~2us, L2 ~6us, LDS ~9us) are far
// below the 54us measured -> the fix is concurrency, not per-step cost.
// New shape: 128x128 block, 4 waves of 64x64 (4x4 MFMA tiles), 2-stage
// double buffer -> LDS 34 KB -> 4 blocks/CU, 1024 blocks co-resident
// exactly (no tail), 16 waves/CU. Independent blocks destagger the
// barrier/vmcnt stalls. Counted waits kept: 4 loads/step, steady-state
// s_waitcnt vmcnt(4); refill issued only after the read-completion
// barrier (2-stage requires it). Lessons kept: XOR swizzle on the global
// gather (0 bank conflicts), verified 16x16x32 C layout, no device
// fences, no shared-line atomics.
__global__ __launch_bounds__(256, 4) void dist_kernel(
    const unsigned short* __restrict__ src_bf,
    const unsigned short* __restrict__ tgt_bf,
    const float* __restrict__ e1, const float* __restrict__ e2,
    const int* __restrict__ labels,
    float* __restrict__ ap_part, float* __restrict__ an_part)
{
    __shared__ unsigned short As[2][BM * BK];   // 2 x 8 KiB
    __shared__ unsigned short Bs[2][BN * BK];   // 2 x 8 KiB
    __shared__ int   li[BM];
    __shared__ int   lj[BN];
    __shared__ float e1s[BM];
    __shared__ float e2s[BN];

    const int i0 = blockIdx.y * BM;
    const int j0 = blockIdx.x * BN;
    const int t = threadIdx.x;
    const int lane = t & 63;
    const int wave = t >> 6;

    if (t < BM) {
        li[t]  = labels[i0 + t];
        e1s[t] = e1[i0 + t];
        lj[t]  = labels[j0 + t];
        e2s[t] = e2[j0 + t];
    }

    // staging: 16B chunks; thread t covers rows srow and srow+64 of both A
    // and B. Physical chunk col t&3 holds logical chunk (t&3)^((srow>>1)&3)
    // (same swizzle key for row and row+64).
    const int srow = t >> 2;                              // 0..63
    const int scol = ((t & 3) ^ ((srow >> 1) & 3)) * 8;   // swizzled source col
    const unsigned short* gA0 = src_bf + (size_t)(i0 + srow) * DIM + scol;
    const unsigned short* gA1 = gA0 + (size_t)64 * DIM;
    const unsigned short* gB0 = tgt_bf + (size_t)(j0 + srow) * DIM + scol;
    const unsigned short* gB1 = gB0 + (size_t)64 * DIM;
    const int off0 = wave * 512;            // rows 0..63 chunk base (shorts)
    const int off1 = 2048 + wave * 512;     // rows 64..127

    // wave -> 64x64 subtile: 2x2 wave grid, 4x4 of 16x16x32 MFMA
    const int wm = (wave >> 1) * 64;
    const int wn = (wave & 1) * 64;
    const int fr = lane & 15;
    const int quad = lane >> 4;
    const int fkey = (fr >> 1) & 3;                       // read-side XOR key
    const int cp = (quad ^ fkey) * 8;                     // physical chunk off

    f32x4 acc[4][4];
    #pragma unroll
    for (int a = 0; a < 4; a++)
        #pragma unroll
        for (int b = 0; b < 4; b++)
            acc[a][b] = (f32x4){0.f, 0.f, 0.f, 0.f};

    // prologue: tiles 0 and 1 -> bufs 0,1 (8 loads in flight)
    #pragma unroll
    for (int p = 0; p < 2; p++) {
        const int kk = p * BK;
        async16(gA0 + kk, &As[p][0] + off0);
        async16(gA1 + kk, &As[p][0] + off1);
        async16(gB0 + kk, &Bs[p][0] + off0);
        async16(gB1 + kk, &Bs[p][0] + off1);
    }

    #pragma unroll
    for (int s = 0; s < NSTEP; s++) {
        if (s == NSTEP - 1) WAIT_VM0();   // only tile 15's 4 loads remain
        else                WAIT_VM4();   // tile s landed; tile s+1 in flight
        RAW_BARRIER();                    // all waves' tile-s DMA landed

        const unsigned short* aa = &As[s & 1][0];
        const unsigned short* bb = &Bs[s & 1][0];
        bf16x8 af[4], bfv[4];
        #pragma unroll
        for (int x = 0; x < 4; x++)
            af[x] = *(const bf16x8*)&aa[(wm + x * 16 + fr) * BK + cp];
        #pragma unroll
        for (int x = 0; x < 4; x++)
            bfv[x] = *(const bf16x8*)&bb[(wn + x * 16 + fr) * BK + cp];
        #pragma unroll
        for (int tm = 0; tm < 4; tm++)
            #pragma unroll
            for (int tn = 0; tn < 4; tn++)
                acc[tm][tn] = __builtin_amdgcn_mfma_f32_16x16x32_bf16(
                    af[tm], bfv[tn], acc[tm][tn], 0, 0, 0);

        if (s + 2 < NSTEP) {
            RAW_BARRIER();    // all reads of buf s&1 done -> safe to refill
            const int kk = (s + 2) * BK;
            const int nb = s & 1;
            async16(gA0 + kk, &As[nb][0] + off0);
            async16(gA1 + kk, &As[nb][0] + off1);
            async16(gB0 + kk, &Bs[nb][0] + off0);
            async16(gB1 + kk, &Bs[nb][0] + off1);
        }
    }

    // epilogue: dist -> masked row max/min -> 16-lane reduce -> partial store
    const float INF = __int_as_float(POS_INF_BITS);
    const int pcol = blockIdx.x * 2 + (wave & 1);        // per-col-wave slot
    #pragma unroll
    for (int tm = 0; tm < 4; tm++) {
        #pragma unroll
        for (int r = 0; r < 4; r++) {
            const int rl = wm + tm * 16 + quad * 4 + r;  // local row 0..127
            const float e1v = e1s[rl];
            const int   liv = li[rl];
            float apv = 0.0f;   // neutral for max (dist >= 0)
            float anv = INF;
            #pragma unroll
            for (int tn = 0; tn < 4; tn++) {
                const int cl = wn + tn * 16 + fr;        // local col 0..127
                float d = e1v + e2s[cl] - 2.0f * acc[tm][tn][r];
                d = fmaxf(d, 0.0f);
                if (liv == lj[cl]) apv = fmaxf(apv, d);
                else               anv = fminf(anv, d);
            }
            #pragma unroll
            for (int off = 1; off < 16; off <<= 1) {
                apv = fmaxf(apv, __shfl_xor(apv, off));
                anv = fminf(anv, __shfl_xor(anv, off));
            }
            if (fr == 0) {
                ap_part[(size_t)(i0 + rl) * NPART + pcol] = apv;
                an_part[(size_t)(i0 + rl) * NPART + pcol] = anv;
            }
        }
    }
}

// 32 blocks x 128 threads; thread = one row: reduce 64 partials, relu, sum.
__global__ __launch_bounds__(128) void loss_kernel(
    const float* __restrict__ ap_part, const float* __restrict__ an_part,
    float* __restrict__ out)
{
    const int row = blockIdx.x * 128 + threadIdx.x;
    const float4* a4 = (const float4*)(ap_part + (size_t)row * NPART);
    const float4* n4 = (const float4*)(an_part + (size_t)row * NPART);
    float apv = 0.0f;
    float anv = __int_as_float(POS_INF_BITS);
    #pragma unroll
    for (int i = 0; i < NPART / 4; i++) {
        float4 a = a4[i], n = n4[i];
        apv = fmaxf(apv, fmaxf(fmaxf(a.x, a.y), fmaxf(a.z, a.w)));
        anv = fminf(anv, fminf(fminf(n.x, n.y), fminf(n.z, n.w)));
    }
    float s = fmaxf(apv - anv + MARGIN_F, 0.0f);
    for (int off = 32; off; off >>= 1) s += __shfl_down(s, off);
    __shared__ float red[2];
    if ((threadIdx.x & 63) == 0) red[threadIdx.x >> 6] = s;
    __syncthreads();
    if (threadIdx.x == 0)
        atomicAdd(out, (red[0] + red[1]) / (float)N_PTS);
}

extern "C" void kernel_launch(void* const* d_in, const int* in_sizes, int n_in,
                              void* d_out, int out_size, void* d_ws, size_t ws_size,
                              hipStream_t stream) {
    const float* src   = (const float*)d_in[0];
    const float* tgt   = (const float*)d_in[1];
    const int* labels  = (const int*)d_in[2];

    char* ws = (char*)d_ws;
    const size_t featB = (size_t)N_PTS * DIM * sizeof(unsigned short);  // 4 MiB
    unsigned short* src_bf = (unsigned short*)ws;
    unsigned short* tgt_bf = (unsigned short*)(ws + featB);
    float* e1 = (float*)(ws + 2 * featB);
    float* e2 = e1 + N_PTS;
    float* ap_part = e2 + N_PTS;                 // [N_PTS][NPART] = 1 MiB
    float* an_part = ap_part + (size_t)N_PTS * NPART;

    prep_kernel<<<N_PTS / 4, 256, 0, stream>>>(src, tgt, src_bf, tgt_bf,
                                               e1, e2, (float*)d_out);
    dim3 grid(N_PTS / BN, N_PTS / BM);
    dist_kernel<<<grid, 256, 0, stream>>>(src_bf, tgt_bf, e1, e2, labels,
                                          ap_part, an_part);
    loss_kernel<<<N_PTS / 128, 128, 0, stream>>>(ap_part, an_part, (float*)d_out);
}

// Round 2
// 98.263 us; speedup vs baseline: 1.0318x; 1.0318x over previous
//
#include <hip/hip_runtime.h>
#include <hip/hip_bf16.h>
#include <stdint.h>

#define N_PTS 4096
#define DIM 512
#define MARGIN_F 0.3f
#define POS_INF_BITS 0x7f800000

typedef short bf16x8 __attribute__((ext_vector_type(8)));
typedef float f32x4 __attribute__((ext_vector_type(4)));

__device__ __forceinline__ unsigned short f2bf(float f) {
    unsigned int b = __float_as_uint(f);
    b += 0x7FFF + ((b >> 16) & 1);   // round-to-nearest-even
    return (unsigned short)(b >> 16);
}

// async global->LDS, 16B per lane; LDS dest is wave-uniform base + lane*16
__device__ __forceinline__ void async16(const unsigned short* g, unsigned short* l) {
    __builtin_amdgcn_global_load_lds(
        (const __attribute__((address_space(1))) unsigned int*)g,
        (__attribute__((address_space(3))) unsigned int*)l,
        16, 0, 0);
}

// Raw barrier / waitcnt: counted vmcnt in steady state, never 0 mid-loop.
#define RAW_BARRIER()  asm volatile("s_barrier" ::: "memory")
#define WAIT_VM8()     asm volatile("s_waitcnt vmcnt(8)" ::: "memory")
#define WAIT_VM0()     asm volatile("s_waitcnt vmcnt(0)" ::: "memory")

// One wave per row: bf16 copy + exact fp32 norms; zero the output accumulator.
__global__ __launch_bounds__(256) void prep_kernel(
    const float* __restrict__ src, const float* __restrict__ tgt,
    unsigned short* __restrict__ src_bf, unsigned short* __restrict__ tgt_bf,
    float* __restrict__ e1, float* __restrict__ e2,
    float* __restrict__ out)
{
    const int row  = blockIdx.x * 4 + (threadIdx.x >> 6);
    const int lane = threadIdx.x & 63;

    if (blockIdx.x == 0 && threadIdx.x == 0) out[0] = 0.0f;

    const float4* s4 = (const float4*)(src + (size_t)row * DIM);
    const float4* t4 = (const float4*)(tgt + (size_t)row * DIM);
    float4 a0 = s4[lane], a1 = s4[lane + 64];
    float4 b0 = t4[lane], b1 = t4[lane + 64];

    ushort4 u;
    ushort4* so = (ushort4*)(src_bf + (size_t)row * DIM);
    ushort4* to = (ushort4*)(tgt_bf + (size_t)row * DIM);
    u.x = f2bf(a0.x); u.y = f2bf(a0.y); u.z = f2bf(a0.z); u.w = f2bf(a0.w); so[lane] = u;
    u.x = f2bf(a1.x); u.y = f2bf(a1.y); u.z = f2bf(a1.z); u.w = f2bf(a1.w); so[lane + 64] = u;
    u.x = f2bf(b0.x); u.y = f2bf(b0.y); u.z = f2bf(b0.z); u.w = f2bf(b0.w); to[lane] = u;
    u.x = f2bf(b1.x); u.y = f2bf(b1.y); u.z = f2bf(b1.z); u.w = f2bf(b1.w); to[lane + 64] = u;

    float s1 = a0.x*a0.x + a0.y*a0.y + a0.z*a0.z + a0.w*a0.w
             + a1.x*a1.x + a1.y*a1.y + a1.z*a1.z + a1.w*a1.w;
    float s2 = b0.x*b0.x + b0.y*b0.y + b0.z*b0.z + b0.w*b0.w
             + b1.x*b1.x + b1.y*b1.y + b1.z*b1.z + b1.w*b1.w;
    for (int off = 32; off; off >>= 1) {
        s1 += __shfl_down(s1, off);
        s2 += __shfl_down(s2, off);
    }
    if (lane == 0) {
        e1[row] = s1;
        e2[row] = s2;
    }
}

#define BM 256
#define BN 256
#define BK 64
#define NSTEP (DIM / BK)   // 8
#define NPART 64           // 16 col-blocks x 4 col-waves

// r12: staged-bytes + MFMA-per-sync over occupancy. r11 post-mortem: 4
// blocks/CU did NOT move timed perf; the shared limiter is (a) 268 MB of
// global_load_lds DMA (A,B re-staged 32x each; ~19 us floor at m97's
// ~22.6 B/cyc/CU DMA rate) and (b) only 16 MFMA/wave between barriers.
// New shape: 256x256 block, BK=64, 512 threads = 8 waves of 128x64
// (8x4 MFMA tiles), double-buffered LDS 132 KB -> exactly 1 block/CU,
// grid 16x16 = 256 blocks, zero tail. Staged bytes halve to 128 MB
// (per-CU 512 KB ~ 9.4 us DMA floor); 64 MFMA/wave/step (~620 cyc of
// matrix work) covers L2 latency + barrier. Loop skeleton unchanged and
// verified: counted vmcnt (steady-state vmcnt(8), never 0 mid-loop),
// refill after read-completion barrier, pre-swizzled global source +
// linear LDS dest. Swizzle generalized to 8-chunk rows: phys chunk =
// logical ^ (row&7); quarter-wave aliasing <= 2-way (free, m136);
// staging key (srow&7) invariant across the 64-row groups.
__global__ __launch_bounds__(512) void dist_kernel(
    const unsigned short* __restrict__ src_bf,
    const unsigned short* __restrict__ tgt_bf,
    const float* __restrict__ e1, const float* __restrict__ e2,
    const int* __restrict__ labels,
    float* __restrict__ ap_part, float* __restrict__ an_part)
{
    __shared__ unsigned short As[2][BM * BK];   // 2 x 32 KiB
    __shared__ unsigned short Bs[2][BN * BK];   // 2 x 32 KiB
    __shared__ int   li[BM];
    __shared__ int   lj[BN];
    __shared__ float e1s[BM];
    __shared__ float e2s[BN];

    const int i0 = blockIdx.y * BM;
    const int j0 = blockIdx.x * BN;
    const int t = threadIdx.x;          // 0..511
    const int lane = t & 63;
    const int wave = t >> 6;            // 0..7

    if (t < BM) {
        li[t]  = labels[i0 + t];
        e1s[t] = e1[i0 + t];
        lj[t]  = labels[j0 + t];
        e2s[t] = e2[j0 + t];
    }

    // staging: rows of 8 x 16B chunks; thread t owns row srow(+64g) chunk
    // t&7. Physical chunk c holds logical chunk c ^ (row&7); since the
    // row groups step by 64, the key (srow&7) is thread-invariant.
    const int srow = t >> 3;                               // 0..63
    const int scol = (((t & 7) ^ (srow & 7))) * 8;         // swizzled col
    const unsigned short* gA = src_bf + (size_t)(i0 + srow) * DIM + scol;
    const unsigned short* gB = tgt_bf + (size_t)(j0 + srow) * DIM + scol;
    const int dOff = wave * 512;        // lane-linear chunk base, + g*4096

    // wave -> 128x64 subtile: 2x4 wave grid, 8x4 of 16x16x32 MFMA
    const int wm = (wave >> 2) * 128;
    const int wn = (wave & 3) * 64;
    const int fr = lane & 15;
    const int quad = lane >> 4;
    const int key = fr & 7;             // read-side XOR key (= row&7)

    f32x4 acc[8][4];
    #pragma unroll
    for (int a = 0; a < 8; a++)
        #pragma unroll
        for (int b = 0; b < 4; b++)
            acc[a][b] = (f32x4){0.f, 0.f, 0.f, 0.f};

    // prologue: tiles 0 and 1 -> bufs 0,1 (16 loads in flight)
    #pragma unroll
    for (int p = 0; p < 2; p++) {
        const int kk = p * BK;
        #pragma unroll
        for (int g = 0; g < 4; g++) {
            async16(gA + (size_t)g * 64 * DIM + kk, &As[p][0] + dOff + g * 4096);
            async16(gB + (size_t)g * 64 * DIM + kk, &Bs[p][0] + dOff + g * 4096);
        }
    }

    #pragma unroll
    for (int s = 0; s < NSTEP; s++) {
        if (s == NSTEP - 1) WAIT_VM0();   // only last tile's 8 loads remain
        else                WAIT_VM8();   // tile s landed; tile s+1 in flight
        RAW_BARRIER();                    // all waves' tile-s DMA landed

        const unsigned short* aa = &As[s & 1][0];
        const unsigned short* bb = &Bs[s & 1][0];
        #pragma unroll
        for (int kh = 0; kh < 2; kh++) {
            const int cp = ((kh * 4 + quad) ^ key) * 8;   // physical chunk
            bf16x8 af[8], bfv[4];
            #pragma unroll
            for (int x = 0; x < 8; x++)
                af[x] = *(const bf16x8*)&aa[(wm + x * 16 + fr) * BK + cp];
            #pragma unroll
            for (int x = 0; x < 4; x++)
                bfv[x] = *(const bf16x8*)&bb[(wn + x * 16 + fr) * BK + cp];
            #pragma unroll
            for (int tm = 0; tm < 8; tm++)
                #pragma unroll
                for (int tn = 0; tn < 4; tn++)
                    acc[tm][tn] = __builtin_amdgcn_mfma_f32_16x16x32_bf16(
                        af[tm], bfv[tn], acc[tm][tn], 0, 0, 0);
        }

        if (s + 2 < NSTEP) {
            RAW_BARRIER();    // all reads of buf s&1 done -> safe to refill
            const int kk = (s + 2) * BK;
            const int nb = s & 1;
            #pragma unroll
            for (int g = 0; g < 4; g++) {
                async16(gA + (size_t)g * 64 * DIM + kk, &As[nb][0] + dOff + g * 4096);
                async16(gB + (size_t)g * 64 * DIM + kk, &Bs[nb][0] + dOff + g * 4096);
            }
        }
    }

    // epilogue: dist -> masked row max/min -> 16-lane reduce -> partial store
    const float INF = __int_as_float(POS_INF_BITS);
    const int pcol = blockIdx.x * 4 + (wave & 3);        // per-col-wave slot
    #pragma unroll
    for (int tm = 0; tm < 8; tm++) {
        #pragma unroll
        for (int r = 0; r < 4; r++) {
            const int rl = wm + tm * 16 + quad * 4 + r;  // local row 0..255
            const float e1v = e1s[rl];
            const int   liv = li[rl];
            float apv = 0.0f;   // neutral for max (dist >= 0)
            float anv = INF;
            #pragma unroll
            for (int tn = 0; tn < 4; tn++) {
                const int cl = wn + tn * 16 + fr;        // local col 0..255
                float d = e1v + e2s[cl] - 2.0f * acc[tm][tn][r];
                d = fmaxf(d, 0.0f);
                if (liv == lj[cl]) apv = fmaxf(apv, d);
                else               anv = fminf(anv, d);
            }
            #pragma unroll
            for (int off = 1; off < 16; off <<= 1) {
                apv = fmaxf(apv, __shfl_xor(apv, off));
                anv = fminf(anv, __shfl_xor(anv, off));
            }
            if (fr == 0) {
                ap_part[(size_t)(i0 + rl) * NPART + pcol] = apv;
                an_part[(size_t)(i0 + rl) * NPART + pcol] = anv;
            }
        }
    }
}

// 32 blocks x 128 threads; thread = one row: reduce 64 partials, relu, sum.
__global__ __launch_bounds__(128) void loss_kernel(
    const float* __restrict__ ap_part, const float* __restrict__ an_part,
    float* __restrict__ out)
{
    const int row = blockIdx.x * 128 + threadIdx.x;
    const float4* a4 = (const float4*)(ap_part + (size_t)row * NPART);
    const float4* n4 = (const float4*)(an_part + (size_t)row * NPART);
    float apv = 0.0f;
    float anv = __int_as_float(POS_INF_BITS);
    #pragma unroll
    for (int i = 0; i < NPART / 4; i++) {
        float4 a = a4[i], n = n4[i];
        apv = fmaxf(apv, fmaxf(fmaxf(a.x, a.y), fmaxf(a.z, a.w)));
        anv = fminf(anv, fminf(fminf(n.x, n.y), fminf(n.z, n.w)));
    }
    float s = fmaxf(apv - anv + MARGIN_F, 0.0f);
    for (int off = 32; off; off >>= 1) s += __shfl_down(s, off);
    __shared__ float red[2];
    if ((threadIdx.x & 63) == 0) red[threadIdx.x >> 6] = s;
    __syncthreads();
    if (threadIdx.x == 0)
        atomicAdd(out, (red[0] + red[1]) / (float)N_PTS);
}

extern "C" void kernel_launch(void* const* d_in, const int* in_sizes, int n_in,
                              void* d_out, int out_size, void* d_ws, size_t ws_size,
                              hipStream_t stream) {
    const float* src   = (const float*)d_in[0];
    const float* tgt   = (const float*)d_in[1];
    const int* labels  = (const int*)d_in[2];

    char* ws = (char*)d_ws;
    const size_t featB = (size_t)N_PTS * DIM * sizeof(unsigned short);  // 4 MiB
    unsigned short* src_bf = (unsigned short*)ws;
    unsigned short* tgt_bf = (unsigned short*)(ws + featB);
    float* e1 = (float*)(ws + 2 * featB);
    float* e2 = e1 + N_PTS;
    float* ap_part = e2 + N_PTS;                 // [N_PTS][NPART] = 1 MiB
    float* an_part = ap_part + (size_t)N_PTS * NPART;

    prep_kernel<<<N_PTS / 4, 256, 0, stream>>>(src, tgt, src_bf, tgt_bf,
                                               e1, e2, (float*)d_out);
    dim3 grid(N_PTS / BN, N_PTS / BM);
    dist_kernel<<<grid, 512, 0, stream>>>(src_bf, tgt_bf, e1, e2, labels,
                                          ap_part, an_part);
    loss_kernel<<<N_PTS / 128, 128, 0, stream>>>(ap_part, an_part, (float*)d_out);
}

// Round 3
// 97.780 us; speedup vs baseline: 1.0369x; 1.0049x over previous
//
#include <hip/hip_runtime.h>
#include <hip/hip_bf16.h>
#include <stdint.h>

#define N_PTS 4096
#define DIM 512
#define MARGIN_F 0.3f
#define POS_INF_BITS 0x7f800000

typedef short bf16x8 __attribute__((ext_vector_type(8)));
typedef float f32x4 __attribute__((ext_vector_type(4)));

__device__ __forceinline__ unsigned short f2bf(float f) {
    unsigned int b = __float_as_uint(f);
    b += 0x7FFF + ((b >> 16) & 1);   // round-to-nearest-even
    return (unsigned short)(b >> 16);
}

// async global->LDS, 16B per lane; LDS dest is wave-uniform base + lane*16
__device__ __forceinline__ void async16(const unsigned short* g, unsigned short* l) {
    __builtin_amdgcn_global_load_lds(
        (const __attribute__((address_space(1))) unsigned int*)g,
        (__attribute__((address_space(3))) unsigned int*)l,
        16, 0, 0);
}

#define RAW_BARRIER()  asm volatile("s_barrier" ::: "memory")
#define WAIT_LGKM0()   asm volatile("s_waitcnt lgkmcnt(0)" ::: "memory")
#define WAIT_VM8()     asm volatile("s_waitcnt vmcnt(8)" ::: "memory")
#define WAIT_VM4()     asm volatile("s_waitcnt vmcnt(4)" ::: "memory")
#define WAIT_VM0()     asm volatile("s_waitcnt vmcnt(0)" ::: "memory")

// One wave per row: bf16 copy + exact fp32 norms; zero the output accumulator.
__global__ __launch_bounds__(256) void prep_kernel(
    const float* __restrict__ src, const float* __restrict__ tgt,
    unsigned short* __restrict__ src_bf, unsigned short* __restrict__ tgt_bf,
    float* __restrict__ e1, float* __restrict__ e2,
    float* __restrict__ out)
{
    const int row  = blockIdx.x * 4 + (threadIdx.x >> 6);
    const int lane = threadIdx.x & 63;

    if (blockIdx.x == 0 && threadIdx.x == 0) out[0] = 0.0f;

    const float4* s4 = (const float4*)(src + (size_t)row * DIM);
    const float4* t4 = (const float4*)(tgt + (size_t)row * DIM);
    float4 a0 = s4[lane], a1 = s4[lane + 64];
    float4 b0 = t4[lane], b1 = t4[lane + 64];

    ushort4 u;
    ushort4* so = (ushort4*)(src_bf + (size_t)row * DIM);
    ushort4* to = (ushort4*)(tgt_bf + (size_t)row * DIM);
    u.x = f2bf(a0.x); u.y = f2bf(a0.y); u.z = f2bf(a0.z); u.w = f2bf(a0.w); so[lane] = u;
    u.x = f2bf(a1.x); u.y = f2bf(a1.y); u.z = f2bf(a1.z); u.w = f2bf(a1.w); so[lane + 64] = u;
    u.x = f2bf(b0.x); u.y = f2bf(b0.y); u.z = f2bf(b0.z); u.w = f2bf(b0.w); to[lane] = u;
    u.x = f2bf(b1.x); u.y = f2bf(b1.y); u.z = f2bf(b1.z); u.w = f2bf(b1.w); to[lane + 64] = u;

    float s1 = a0.x*a0.x + a0.y*a0.y + a0.z*a0.z + a0.w*a0.w
             + a1.x*a1.x + a1.y*a1.y + a1.z*a1.z + a1.w*a1.w;
    float s2 = b0.x*b0.x + b0.y*b0.y + b0.z*b0.z + b0.w*b0.w
             + b1.x*b1.x + b1.y*b1.y + b1.z*b1.z + b1.w*b1.w;
    for (int off = 32; off; off >>= 1) {
        s1 += __shfl_down(s1, off);
        s2 += __shfl_down(s2, off);
    }
    if (lane == 0) {
        e1[row] = s1;
        e2[row] = s2;
    }
}

#define BM 256
#define BN 256
#define BK 64
#define NKT (DIM / BK)     // 8 K-tiles
#define NIT (NKT / 2)      // 4 iterations x 2 K-tiles
#define NPART 64           // 16 col-blocks x 4 col-waves

// r13: 8-phase schedule (m201 port) on the r12 geometry. r12 post-mortem:
// 256x256/BK=64 2-phase loop stuck ~43us (~400 TF) with all pipes idle --
// exactly the measured 2-phase regime (m230: 682 TF) whose stage+vmcnt+
// barrier path is 72% of time (m233). The proven fix at THIS geometry is
// the 8-phase counted-vmcnt schedule (m201: 1563 TF, +setprio per m218b).
// Per iteration (2 K-tiles): 8 phases, each {4 ds_read_b128 af (+8 bfv at
// tile entry) | issue one 16KB half-tile stage | barrier | lgkmcnt(0) |
// setprio(1) 16 MFMA setprio(0) | [vmcnt(4) at ph3/ph7] | barrier}.
// Region-liveness-derived stage slots: P1/P2->A(2i+1) (buf1.A dead after
// prev P8, read this P5, gated by P4 vmcnt(4)); P3/P4->B(2i+2) (buf0.B
// dead after P1); P5/P6->A(2i+2) (buf0.A dead after P4); P7/P8->B(2i+3)
// (buf1.B dead after P5). vmcnt(4) at P4/P8-close = everything but the
// newest half-tile-pair landed; never vmcnt(0) mid-loop. Kept verified:
// XOR chunk swizzle (phys = logical ^ (row&7)) on both stage-source and
// ds_read sides, 16x16x32 C layout, masked-reduce epilogue, NPART=64.
__global__ __launch_bounds__(512) void dist_kernel(
    const unsigned short* __restrict__ src_bf,
    const unsigned short* __restrict__ tgt_bf,
    const float* __restrict__ e1, const float* __restrict__ e2,
    const int* __restrict__ labels,
    float* __restrict__ ap_part, float* __restrict__ an_part)
{
    __shared__ unsigned short As[2][BM * BK];   // 2 x 32 KiB (buf0=even KT, buf1=odd)
    __shared__ unsigned short Bs[2][BN * BK];   // 2 x 32 KiB
    __shared__ int   li[BM];
    __shared__ int   lj[BN];
    __shared__ float e1s[BM];
    __shared__ float e2s[BN];

    const int i0 = blockIdx.y * BM;
    const int j0 = blockIdx.x * BN;
    const int t = threadIdx.x;          // 0..511
    const int lane = t & 63;
    const int wave = t >> 6;            // 0..7

    if (t < BM) {
        li[t]  = labels[i0 + t];
        e1s[t] = e1[i0 + t];
        lj[t]  = labels[j0 + t];
        e2s[t] = e2[j0 + t];
    }

    // staging: rows of 8 x 16B chunks; thread t owns row srow(+64g), chunk
    // t&7. Physical chunk c holds logical chunk c ^ (row&7); key (srow&7)
    // is invariant across the 64-row groups. Half-tile h = groups {2h,2h+1}
    // of one matrix (128 rows x 64 K = 16KB = 2 async16/thread).
    const int srow = t >> 3;                               // 0..63
    const int scol = (((t & 7) ^ (srow & 7))) * 8;         // swizzled col
    const unsigned short* gA = src_bf + (size_t)(i0 + srow) * DIM + scol;
    const unsigned short* gB = tgt_bf + (size_t)(j0 + srow) * DIM + scol;
    const int dOff = wave * 512;        // lane-linear chunk base, + g*4096

#define STAGE_A(buf, kt, h) do { \
        async16(gA + (size_t)(2*(h))   * 64 * DIM + (kt) * BK, &As[buf][0] + dOff + (2*(h))   * 4096); \
        async16(gA + (size_t)(2*(h)+1) * 64 * DIM + (kt) * BK, &As[buf][0] + dOff + (2*(h)+1) * 4096); \
    } while (0)
#define STAGE_B(buf, kt, h) do { \
        async16(gB + (size_t)(2*(h))   * 64 * DIM + (kt) * BK, &Bs[buf][0] + dOff + (2*(h))   * 4096); \
        async16(gB + (size_t)(2*(h)+1) * 64 * DIM + (kt) * BK, &Bs[buf][0] + dOff + (2*(h)+1) * 4096); \
    } while (0)

    // wave -> 128x64 subtile: 2x4 wave grid, 8x4 of 16x16x32 MFMA
    const int wm = (wave >> 2) * 128;
    const int wn = (wave & 3) * 64;
    const int fr = lane & 15;
    const int quad = lane >> 4;
    const int key = fr & 7;             // read-side XOR key (= row&7)

    f32x4 acc[8][4];
    #pragma unroll
    for (int a = 0; a < 8; a++)
        #pragma unroll
        for (int b = 0; b < 4; b++)
            acc[a][b] = (f32x4){0.f, 0.f, 0.f, 0.f};

    // prologue: T0 -> buf0 (8 loads), then T1 -> buf1 (8 loads);
    // wait T0 only (vmcnt(8)), T1 gated later by iter-0 P4's vmcnt(4).
    STAGE_A(0, 0, 0); STAGE_A(0, 0, 1);
    STAGE_B(0, 0, 0); STAGE_B(0, 0, 1);
    STAGE_A(1, 1, 0); STAGE_A(1, 1, 1);
    STAGE_B(1, 1, 0); STAGE_B(1, 1, 1);
    WAIT_VM8();
    RAW_BARRIER();

    bf16x8 bfv[4][2];   // B fragments, live across the 4 phases of a K-tile
    bf16x8 af[2][2];    // A fragments, per phase

    #pragma unroll
    for (int it = 0; it < NIT; ++it) {
        #pragma unroll
        for (int ph = 0; ph < 8; ++ph) {
            const int half = ph >> 2;          // 0: tile 2it (buf0), 1: 2it+1 (buf1)
            const int q = ph & 3;              // tm pair index
            const unsigned short* aa = &As[half][0];
            const unsigned short* bb = &Bs[half][0];

            // --- phase-top ds reads (gated by prev phase's vmcnt+barrier) ---
            if (q == 0) {
                #pragma unroll
                for (int x = 0; x < 4; ++x)
                    #pragma unroll
                    for (int kh = 0; kh < 2; ++kh)
                        bfv[x][kh] = *(const bf16x8*)
                            &bb[(wn + x * 16 + fr) * BK + ((kh * 4 + quad) ^ key) * 8];
            }
            #pragma unroll
            for (int x = 0; x < 2; ++x)
                #pragma unroll
                for (int kh = 0; kh < 2; ++kh)
                    af[x][kh] = *(const bf16x8*)
                        &aa[(wm + (2 * q + x) * 16 + fr) * BK + ((kh * 4 + quad) ^ key) * 8];

            // --- stage slot (one half-tile; target region provably dead) ---
            if (ph == 0) { if (it > 0)       STAGE_A(1, 2 * it + 1, 0); }
            if (ph == 1) { if (it > 0)       STAGE_A(1, 2 * it + 1, 1); }
            if (ph == 2) { if (it < NIT - 1) STAGE_B(0, 2 * it + 2, 0); }
            if (ph == 3) { if (it < NIT - 1) STAGE_B(0, 2 * it + 2, 1); }
            if (ph == 4) { if (it < NIT - 1) STAGE_A(0, 2 * it + 2, 0); }
            if (ph == 5) { if (it < NIT - 1) STAGE_A(0, 2 * it + 2, 1); }
            if (ph == 6) { if (it < NIT - 1) STAGE_B(1, 2 * it + 3, 0); }
            if (ph == 7) { if (it < NIT - 1) STAGE_B(1, 2 * it + 3, 1); }

            RAW_BARRIER();
            WAIT_LGKM0();

            __builtin_amdgcn_s_setprio(1);
            #pragma unroll
            for (int x = 0; x < 2; ++x)
                #pragma unroll
                for (int tn = 0; tn < 4; ++tn)
                    #pragma unroll
                    for (int kh = 0; kh < 2; ++kh)
                        acc[2 * q + x][tn] = __builtin_amdgcn_mfma_f32_16x16x32_bf16(
                            af[x][kh], bfv[tn][kh], acc[2 * q + x][tn], 0, 0, 0);
            __builtin_amdgcn_s_setprio(0);

            // --- counted vmcnt gates, only at phases 4 and 8 ---
            if (ph == 3) { if (it < NIT - 1) WAIT_VM4(); else WAIT_VM0(); }
            if (ph == 7) { if (it < NIT - 1) WAIT_VM4(); }
            RAW_BARRIER();
        }
    }

    // epilogue: dist -> masked row max/min -> 16-lane reduce -> partial store
    const float INF = __int_as_float(POS_INF_BITS);
    const int pcol = blockIdx.x * 4 + (wave & 3);        // per-col-wave slot
    #pragma unroll
    for (int tm = 0; tm < 8; tm++) {
        #pragma unroll
        for (int r = 0; r < 4; r++) {
            const int rl = wm + tm * 16 + quad * 4 + r;  // local row 0..255
            const float e1v = e1s[rl];
            const int   liv = li[rl];
            float apv = 0.0f;   // neutral for max (dist >= 0)
            float anv = INF;
            #pragma unroll
            for (int tn = 0; tn < 4; tn++) {
                const int cl = wn + tn * 16 + fr;        // local col 0..255
                float d = e1v + e2s[cl] - 2.0f * acc[tm][tn][r];
                d = fmaxf(d, 0.0f);
                if (liv == lj[cl]) apv = fmaxf(apv, d);
                else               anv = fminf(anv, d);
            }
            #pragma unroll
            for (int off = 1; off < 16; off <<= 1) {
                apv = fmaxf(apv, __shfl_xor(apv, off));
                anv = fminf(anv, __shfl_xor(anv, off));
            }
            if (fr == 0) {
                ap_part[(size_t)(i0 + rl) * NPART + pcol] = apv;
                an_part[(size_t)(i0 + rl) * NPART + pcol] = anv;
            }
        }
    }
#undef STAGE_A
#undef STAGE_B
}

// 32 blocks x 128 threads; thread = one row: reduce 64 partials, relu, sum.
__global__ __launch_bounds__(128) void loss_kernel(
    const float* __restrict__ ap_part, const float* __restrict__ an_part,
    float* __restrict__ out)
{
    const int row = blockIdx.x * 128 + threadIdx.x;
    const float4* a4 = (const float4*)(ap_part + (size_t)row * NPART);
    const float4* n4 = (const float4*)(an_part + (size_t)row * NPART);
    float apv = 0.0f;
    float anv = __int_as_float(POS_INF_BITS);
    #pragma unroll
    for (int i = 0; i < NPART / 4; i++) {
        float4 a = a4[i], n = n4[i];
        apv = fmaxf(apv, fmaxf(fmaxf(a.x, a.y), fmaxf(a.z, a.w)));
        anv = fminf(anv, fminf(fminf(n.x, n.y), fminf(n.z, n.w)));
    }
    float s = fmaxf(apv - anv + MARGIN_F, 0.0f);
    for (int off = 32; off; off >>= 1) s += __shfl_down(s, off);
    __shared__ float red[2];
    if ((threadIdx.x & 63) == 0) red[threadIdx.x >> 6] = s;
    __syncthreads();
    if (threadIdx.x == 0)
        atomicAdd(out, (red[0] + red[1]) / (float)N_PTS);
}

extern "C" void kernel_launch(void* const* d_in, const int* in_sizes, int n_in,
                              void* d_out, int out_size, void* d_ws, size_t ws_size,
                              hipStream_t stream) {
    const float* src   = (const float*)d_in[0];
    const float* tgt   = (const float*)d_in[1];
    const int* labels  = (const int*)d_in[2];

    char* ws = (char*)d_ws;
    const size_t featB = (size_t)N_PTS * DIM * sizeof(unsigned short);  // 4 MiB
    unsigned short* src_bf = (unsigned short*)ws;
    unsigned short* tgt_bf = (unsigned short*)(ws + featB);
    float* e1 = (float*)(ws + 2 * featB);
    float* e2 = e1 + N_PTS;
    float* ap_part = e2 + N_PTS;                 // [N_PTS][NPART] = 1 MiB
    float* an_part = ap_part + (size_t)N_PTS * NPART;

    prep_kernel<<<N_PTS / 4, 256, 0, stream>>>(src, tgt, src_bf, tgt_bf,
                                               e1, e2, (float*)d_out);
    dim3 grid(N_PTS / BN, N_PTS / BM);
    dist_kernel<<<grid, 512, 0, stream>>>(src_bf, tgt_bf, e1, e2, labels,
                                          ap_part, an_part);
    loss_kernel<<<N_PTS / 128, 128, 0, stream>>>(ap_part, an_part, (float*)d_out);
}